// Round 12
// baseline (38.830 us; speedup 1.0000x reference)
//
#include <hip/hip_runtime.h>
#include <hip/hip_bf16.h>
#include <math.h>

// AFM: B=4096, F=24, D=64, A=64, P=F*(F-1)/2=276
#define NF 24
#define ND 64
#define NA 64
#define NP 276
#define NPAD 288
#define NTILE 18
#define NT 128      // 2 waves per block, ONE batch per block; waves split tiles

typedef short bf16x8 __attribute__((ext_vector_type(8)));
typedef float f32x4  __attribute__((ext_vector_type(4)));

__device__ __forceinline__ short f2bf(float f) {
    __hip_bfloat16 h = __float2bfloat16(f);      // RNE
    union { __hip_bfloat16 h; unsigned short u; } cv;
    cv.h = h;
    return (short)cv.u;
}
__device__ __forceinline__ float bf2f(short s) {
    union { unsigned u; float f; } cv;
    cv.u = ((unsigned)(unsigned short)s) << 16;
    return cv.f;
}

// ---- DPP helpers (VALU-pipe cross-lane, no LDS); ctrl must be constexpr ----
template <int CTRL, int RMASK>
__device__ __forceinline__ float dpp_add_step(float v) {
    int moved = __builtin_amdgcn_update_dpp(0, __float_as_int(v), CTRL, RMASK, 0xf, true);
    return v + __int_as_float(moved);
}
template <int CTRL, int RMASK>
__device__ __forceinline__ float dpp_max_step(float v) {
    int moved = __builtin_amdgcn_update_dpp(__float_as_int(v), __float_as_int(v), CTRL, RMASK, 0xf, false);
    return fmaxf(v, __int_as_float(moved));
}
// sum of each 16-lane row, result valid at lane 0 of the row (row_shl)
__device__ __forceinline__ float row16_sum0(float v) {
    v = dpp_add_step<0x101, 0xf>(v);   // row_shl 1
    v = dpp_add_step<0x102, 0xf>(v);   // row_shl 2
    v = dpp_add_step<0x104, 0xf>(v);   // row_shl 4
    v = dpp_add_step<0x108, 0xf>(v);   // row_shl 8
    return v;
}
__device__ __forceinline__ float wave_sum(float v) {
    v = dpp_add_step<0x111, 0xf>(v);   // row_shr 1
    v = dpp_add_step<0x112, 0xf>(v);   // row_shr 2
    v = dpp_add_step<0x114, 0xf>(v);   // row_shr 4
    v = dpp_add_step<0x118, 0xf>(v);   // row_shr 8
    v = dpp_add_step<0x142, 0xa>(v);   // row_bcast:15 -> rows 1,3
    v = dpp_add_step<0x143, 0xc>(v);   // row_bcast:31 -> rows 2,3
    return __int_as_float(__builtin_amdgcn_readlane(__float_as_int(v), 63));
}
__device__ __forceinline__ float wave_max(float v) {
    v = dpp_max_step<0x111, 0xf>(v);
    v = dpp_max_step<0x112, 0xf>(v);
    v = dpp_max_step<0x114, 0xf>(v);
    v = dpp_max_step<0x118, 0xf>(v);
    v = dpp_max_step<0x142, 0xa>(v);
    v = dpp_max_step<0x143, 0xc>(v);
    return __int_as_float(__builtin_amdgcn_readlane(__float_as_int(v), 63));
}

// ws layout (shorts):
//   [0, 4096)    waF:  [lane 64][chunk 8 = nt*2+kh][8 bf16]
//   [4096, 5120) wfcF: [lane 64][kh 2][8 bf16]  (col0=hi, col1=lo)
//   [5120, 5696) rc:   288 ints, packed (r<<16)|c, pad pairs = (0,0)
__global__ __launch_bounds__(64) void afm_prep_kernel(
    const float* __restrict__ Wa,
    const float* __restrict__ Wfc,
    short* __restrict__ ws)
{
    const int l  = (int)threadIdx.x;
    const int lg = l >> 4, li = l & 15;
    short* waF  = ws;
    short* wfcF = ws + 64 * 64;
    int*   rc   = (int*)(ws + 64 * 64 + 64 * 16);
    #pragma unroll
    for (int nt = 0; nt < 4; ++nt)
        #pragma unroll
        for (int kh = 0; kh < 2; ++kh)
            #pragma unroll
            for (int i = 0; i < 8; ++i) {
                int d = kh * 32 + lg * 8 + i;
                waF[l * 64 + (nt * 2 + kh) * 8 + i] = f2bf(Wa[d * NA + nt * 16 + li]);
            }
    #pragma unroll
    for (int kh = 0; kh < 2; ++kh)
        #pragma unroll
        for (int i = 0; i < 8; ++i) {
            int d = kh * 32 + lg * 8 + i;
            float w = Wfc[d];
            short hi = f2bf(w);
            short lo = f2bf(w - bf2f(hi));
            wfcF[l * 16 + kh * 8 + i] = (li == 0) ? hi : ((li == 1) ? lo : (short)0);
        }
    for (int p0 = l; p0 < NPAD; p0 += 64) {
        int r = 0, c = 0;
        if (p0 < NP) {
            int rem = p0;
            while (rem >= NF - 1 - r) { rem -= NF - 1 - r; ++r; }
            c = r + 1 + rem;
        }
        rc[p0] = (r << 16) | c;
    }
}

__global__ __launch_bounds__(NT) void afm_mfma_kernel(
    const float* __restrict__ x,
    const float* __restrict__ ba,
    const float* __restrict__ Wp,
    const float* __restrict__ bfc,
    const short* __restrict__ ws,
    float* __restrict__ out)
{
    const int tid  = (int)threadIdx.x;
    const int lane = tid & 63;
    const int wid  = tid >> 6;          // 0 or 1: tile-splitting waves
    const int b    = blockIdx.x;        // one batch per block
    const int lg   = lane >> 4;
    const int li   = lane & 15;

    __shared__ float  xs[NF][68];       // one copy, shared by both waves
    __shared__ float2 lv[NPAD];         // {logit, v} per pair

    // ---- stage x[b] into LDS (both waves participate) ----
    const float4* xb4 = (const float4*)(x + (size_t)b * (NF * ND));
    #pragma unroll
    for (int k = 0; k < 3; ++k) {
        int i = tid + k * NT;            // 0..383
        float4 v = xb4[i];
        *(float4*)&xs[i >> 4][(i & 15) * 4] = v;
    }

    // ---- fragments from ws: 10 vector loads, no cvt ----
    const bf16x8* waF  = (const bf16x8*)ws;              // [64][8]
    const bf16x8* wfcF = (const bf16x8*)(ws + 64 * 64);  // [64][2]
    const int*    rcg  = (const int*)(ws + 64 * 64 + 64 * 16);
    bf16x8 WaF[4][2];
    #pragma unroll
    for (int nt = 0; nt < 4; ++nt)
        #pragma unroll
        for (int kh = 0; kh < 2; ++kh)
            WaF[nt][kh] = waF[lane * 8 + nt * 2 + kh];
    bf16x8 WfcF[2] = { wfcF[lane * 2 + 0], wfcF[lane * 2 + 1] };

    float ba_reg[4], wp_reg[4];
    #pragma unroll
    for (int nt = 0; nt < 4; ++nt) {
        ba_reg[nt] = ba[nt * 16 + li];
        wp_reg[nt] = Wp[nt * 16 + li];
    }

    __syncthreads();

    // ---- tile loop: wave w handles tiles t = w, w+2, ... (9 each) ----
    for (int t = wid; t < NTILE; t += 2) {
        int pr = rcg[t * 16 + li];       // L1-resident pair table
        int rI = pr >> 16, cI = pr & 0xffff;

        bf16x8 Ah[2];
        #pragma unroll
        for (int kh = 0; kh < 2; ++kh) {
            int d0 = kh * 32 + lg * 8;
            const float4* prp = reinterpret_cast<const float4*>(&xs[rI][d0]);
            const float4* pcp = reinterpret_cast<const float4*>(&xs[cI][d0]);
            float4 r0 = prp[0], r1 = prp[1];
            float4 c0 = pcp[0], c1 = pcp[1];
            Ah[kh][0] = f2bf(r0.x * c0.x);
            Ah[kh][1] = f2bf(r0.y * c0.y);
            Ah[kh][2] = f2bf(r0.z * c0.z);
            Ah[kh][3] = f2bf(r0.w * c0.w);
            Ah[kh][4] = f2bf(r1.x * c1.x);
            Ah[kh][5] = f2bf(r1.y * c1.y);
            Ah[kh][6] = f2bf(r1.z * c1.z);
            Ah[kh][7] = f2bf(r1.w * c1.w);
        }

        f32x4 acc[4];
        #pragma unroll
        for (int nt = 0; nt < 4; ++nt) {
            acc[nt] = (f32x4){0.f, 0.f, 0.f, 0.f};
            acc[nt] = __builtin_amdgcn_mfma_f32_16x16x32_bf16(Ah[0], WaF[nt][0], acc[nt], 0, 0, 0);
            acc[nt] = __builtin_amdgcn_mfma_f32_16x16x32_bf16(Ah[1], WaF[nt][1], acc[nt], 0, 0, 0);
        }
        f32x4 accv = (f32x4){0.f, 0.f, 0.f, 0.f};
        accv = __builtin_amdgcn_mfma_f32_16x16x32_bf16(Ah[0], WfcF[0], accv, 0, 0, 0);
        accv = __builtin_amdgcn_mfma_f32_16x16x32_bf16(Ah[1], WfcF[1], accv, 0, 0, 0);

        // epilogue: DPP row reduce (VALU pipe), write {logit, v} at li==0
        #pragma unroll
        for (int j = 0; j < 4; ++j) {
            float lsum = 0.f;
            #pragma unroll
            for (int nt = 0; nt < 4; ++nt) {
                float h = fmaxf(acc[nt][j] + ba_reg[nt], 0.f);
                lsum = fmaf(h, wp_reg[nt], lsum);
            }
            lsum = row16_sum0(lsum);                       // sum over 16 cols -> li==0
            int moved = __builtin_amdgcn_update_dpp(       // quad_perm(1,0,3,2)
                0, __float_as_int(accv[j]), 0xB1, 0xf, 0xf, true);
            float vv = accv[j] + __int_as_float(moved);    // col0(hi)+col1(lo) at li==0
            int row = t * 16 + lg * 4 + j;                 // C/D: col=li, row=lg*4+j
            if (li == 0)
                lv[row] = make_float2(lsum, vv);           // rows>=NP are pad, never read
        }
    }

    __syncthreads();

    // ---- softmax fused with output (both waves compute; wave0 lane0 writes) ----
    float2 myv[5];
    float m = -INFINITY;
    #pragma unroll
    for (int k = 0; k < 5; ++k) {
        int p = lane + k * 64;
        if (p < NP) { myv[k] = lv[p]; m = fmaxf(m, myv[k].x); }
        else        { myv[k] = make_float2(-INFINITY, 0.f); }
    }
    m = wave_max(m);

    float se = 0.f, sev = 0.f;
    #pragma unroll
    for (int k = 0; k < 5; ++k) {
        int p = lane + k * 64;
        if (p < NP) {
            float e = __expf(myv[k].x - m);
            se += e;
            sev = fmaf(e, myv[k].y, sev);
        }
    }
    se  = wave_sum(se);
    sev = wave_sum(sev);
    if (tid == 0)
        out[b] = sev / se + bfc[0];
}

extern "C" void kernel_launch(void* const* d_in, const int* in_sizes, int n_in,
                              void* d_out, int out_size, void* d_ws, size_t ws_size,
                              hipStream_t stream) {
    const float* x   = (const float*)d_in[0];
    const float* Wa  = (const float*)d_in[1];
    const float* ba  = (const float*)d_in[2];
    const float* Wp  = (const float*)d_in[3];
    // d_in[4] = bp  (unused: softmax shift-invariant)
    const float* Wfc = (const float*)d_in[5];
    const float* bfc = (const float*)d_in[6];
    float* out = (float*)d_out;
    short* ws  = (short*)d_ws;

    const int B = in_sizes[0] / (NF * ND);
    hipLaunchKernelGGL(afm_prep_kernel, dim3(1), dim3(64), 0, stream, Wa, Wfc, ws);
    hipLaunchKernelGGL(afm_mfma_kernel, dim3(B), dim3(NT), 0, stream,
                       x, ba, Wp, bfc, ws, out);
}

// Round 13
// 34.690 us; speedup vs baseline: 1.1193x; 1.1193x over previous
//
#include <hip/hip_runtime.h>
#include <hip/hip_bf16.h>
#include <math.h>

// AFM: B=4096, F=24, D=64, A=64, P=F*(F-1)/2=276
#define NF 24
#define ND 64
#define NA 64
#define NP 276
#define NPAD 288
#define NTILE 18
#define NT 256      // 4 waves per block; wave w handles batch blockIdx*4+w
#define BPB 4

typedef short bf16x8 __attribute__((ext_vector_type(8)));
typedef float f32x4  __attribute__((ext_vector_type(4)));

__device__ __forceinline__ short f2bf(float f) {
    __hip_bfloat16 h = __float2bfloat16(f);      // RNE
    union { __hip_bfloat16 h; unsigned short u; } cv;
    cv.h = h;
    return (short)cv.u;
}
__device__ __forceinline__ float bf2f(short s) {
    union { unsigned u; float f; } cv;
    cv.u = ((unsigned)(unsigned short)s) << 16;
    return cv.f;
}

// ---- DPP helpers for the final wave-wide softmax reduce ----
template <int CTRL, int RMASK>
__device__ __forceinline__ float dpp_add_step(float v) {
    int moved = __builtin_amdgcn_update_dpp(0, __float_as_int(v), CTRL, RMASK, 0xf, true);
    return v + __int_as_float(moved);
}
template <int CTRL, int RMASK>
__device__ __forceinline__ float dpp_max_step(float v) {
    int moved = __builtin_amdgcn_update_dpp(__float_as_int(v), __float_as_int(v), CTRL, RMASK, 0xf, false);
    return fmaxf(v, __int_as_float(moved));
}
__device__ __forceinline__ float wave_sum(float v) {
    v = dpp_add_step<0x111, 0xf>(v);   // row_shr 1
    v = dpp_add_step<0x112, 0xf>(v);   // row_shr 2
    v = dpp_add_step<0x114, 0xf>(v);   // row_shr 4
    v = dpp_add_step<0x118, 0xf>(v);   // row_shr 8
    v = dpp_add_step<0x142, 0xa>(v);   // row_bcast:15 -> rows 1,3
    v = dpp_add_step<0x143, 0xc>(v);   // row_bcast:31 -> rows 2,3
    return __int_as_float(__builtin_amdgcn_readlane(__float_as_int(v), 63));
}
__device__ __forceinline__ float wave_max(float v) {
    v = dpp_max_step<0x111, 0xf>(v);
    v = dpp_max_step<0x112, 0xf>(v);
    v = dpp_max_step<0x114, 0xf>(v);
    v = dpp_max_step<0x118, 0xf>(v);
    v = dpp_max_step<0x142, 0xa>(v);
    v = dpp_max_step<0x143, 0xc>(v);
    return __int_as_float(__builtin_amdgcn_readlane(__float_as_int(v), 63));
}

// ws layout (shorts):
//   [0, 4096)    waF:  [lane 64][chunk 8 = nt*2+kh][8 bf16]
//   [4096, 5120) wfcF: [lane 64][kh 2][8 bf16]  (row0=hi, row1=lo as A-operand)
//   [5120, 5696) rc:   288 ints, packed (r<<16)|c, pad pairs = (0,0)
__global__ __launch_bounds__(64) void afm_prep_kernel(
    const float* __restrict__ Wa,
    const float* __restrict__ Wfc,
    short* __restrict__ ws)
{
    const int l  = (int)threadIdx.x;
    const int lg = l >> 4, li = l & 15;
    short* waF  = ws;
    short* wfcF = ws + 64 * 64;
    int*   rc   = (int*)(ws + 64 * 64 + 64 * 16);
    #pragma unroll
    for (int nt = 0; nt < 4; ++nt)
        #pragma unroll
        for (int kh = 0; kh < 2; ++kh)
            #pragma unroll
            for (int i = 0; i < 8; ++i) {
                int d = kh * 32 + lg * 8 + i;
                waF[l * 64 + (nt * 2 + kh) * 8 + i] = f2bf(Wa[d * NA + nt * 16 + li]);
            }
    #pragma unroll
    for (int kh = 0; kh < 2; ++kh)
        #pragma unroll
        for (int i = 0; i < 8; ++i) {
            int d = kh * 32 + lg * 8 + i;
            float w = Wfc[d];
            short hi = f2bf(w);
            short lo = f2bf(w - bf2f(hi));
            wfcF[l * 16 + kh * 8 + i] = (li == 0) ? hi : ((li == 1) ? lo : (short)0);
        }
    for (int p0 = l; p0 < NPAD; p0 += 64) {
        int r = 0, c = 0;
        if (p0 < NP) {
            int rem = p0;
            while (rem >= NF - 1 - r) { rem -= NF - 1 - r; ++r; }
            c = r + 1 + rem;
        }
        rc[p0] = (r << 16) | c;
    }
}

__global__ __launch_bounds__(NT) void afm_mfma_kernel(
    const float* __restrict__ x,
    const float* __restrict__ ba,
    const float* __restrict__ Wp,
    const float* __restrict__ bfc,
    const short* __restrict__ ws,
    float* __restrict__ out)
{
    const int tid  = (int)threadIdx.x;
    const int lane = tid & 63;
    const int wid  = tid >> 6;
    const int b    = blockIdx.x * BPB + wid;   // this wave's batch
    const int lg   = lane >> 4;
    const int li   = lane & 15;

    __shared__ float  xs[BPB][NF][68];   // per-wave x tile (float4-aligned rows)
    __shared__ float2 lv[BPB][NPAD];     // per-wave {logit, v}

    // ---- stage x[b] into this wave's LDS region (no cross-wave deps) ----
    const float4* xb4 = (const float4*)(x + (size_t)b * (NF * ND));
    #pragma unroll
    for (int k = 0; k < 6; ++k) {
        int i = lane + k * 64;           // 0..383
        float4 v = xb4[i];
        *(float4*)&xs[wid][i >> 4][(i & 15) * 4] = v;
    }

    // ---- fragments from ws: 10 vector loads, no cvt ----
    const bf16x8* waF  = (const bf16x8*)ws;              // [64][8]
    const bf16x8* wfcF = (const bf16x8*)(ws + 64 * 64);  // [64][2]
    const int*    rcg  = (const int*)(ws + 64 * 64 + 64 * 16);
    bf16x8 WaF[4][2];
    #pragma unroll
    for (int nt = 0; nt < 4; ++nt)
        #pragma unroll
        for (int kh = 0; kh < 2; ++kh)
            WaF[nt][kh] = waF[lane * 8 + nt * 2 + kh];
    bf16x8 WfcF[2] = { wfcF[lane * 2 + 0], wfcF[lane * 2 + 1] };

    // per-lane unit arrays: unit = nt*16 + lg*4 + j  (C/D row under swapped MFMA)
    float ba_t[4][4], wp_t[4][4];
    #pragma unroll
    for (int nt = 0; nt < 4; ++nt)
        #pragma unroll
        for (int j = 0; j < 4; ++j) {
            ba_t[nt][j] = ba[nt * 16 + lg * 4 + j];
            wp_t[nt][j] = Wp[nt * 16 + lg * 4 + j];
        }

    // in-wave ordering of staging writes vs tile reads (compiler also tracks)
    asm volatile("s_waitcnt lgkmcnt(0)" ::: "memory");

    // ---- tile loop: ip(bf16) -> D = Wa^T@ip^T (+ba via C-init) -> logits, v ----
    for (int t = 0; t < NTILE; ++t) {
        int pr = rcg[t * 16 + li];       // L1-resident pair table
        int rI = pr >> 16, cI = pr & 0xffff;

        bf16x8 Ah[2];
        #pragma unroll
        for (int kh = 0; kh < 2; ++kh) {
            int d0 = kh * 32 + lg * 8;
            const float4* prp = reinterpret_cast<const float4*>(&xs[wid][rI][d0]);
            const float4* pcp = reinterpret_cast<const float4*>(&xs[wid][cI][d0]);
            float4 r0 = prp[0], r1 = prp[1];
            float4 c0 = pcp[0], c1 = pcp[1];
            Ah[kh][0] = f2bf(r0.x * c0.x);
            Ah[kh][1] = f2bf(r0.y * c0.y);
            Ah[kh][2] = f2bf(r0.z * c0.z);
            Ah[kh][3] = f2bf(r0.w * c0.w);
            Ah[kh][4] = f2bf(r1.x * c1.x);
            Ah[kh][5] = f2bf(r1.y * c1.y);
            Ah[kh][6] = f2bf(r1.z * c1.z);
            Ah[kh][7] = f2bf(r1.w * c1.w);
        }

        // swapped operands: A = Wa^T fragment, B = ip fragment (identical fills,
        // the A-layout row=lane&15 / B-layout col=lane&15 are both already
        // HW-verified by the previous passing kernels). D[unit, pair].
        f32x4 acc[4];
        #pragma unroll
        for (int nt = 0; nt < 4; ++nt) {
            acc[nt] = (f32x4){ba_t[nt][0], ba_t[nt][1], ba_t[nt][2], ba_t[nt][3]};
            acc[nt] = __builtin_amdgcn_mfma_f32_16x16x32_bf16(WaF[nt][0], Ah[0], acc[nt], 0, 0, 0);
            acc[nt] = __builtin_amdgcn_mfma_f32_16x16x32_bf16(WaF[nt][1], Ah[1], acc[nt], 0, 0, 0);
        }
        f32x4 accv = (f32x4){0.f, 0.f, 0.f, 0.f};
        accv = __builtin_amdgcn_mfma_f32_16x16x32_bf16(WfcF[0], Ah[0], accv, 0, 0, 0);
        accv = __builtin_amdgcn_mfma_f32_16x16x32_bf16(WfcF[1], Ah[1], accv, 0, 0, 0);

        // epilogue: within-lane relu+Wp dot over this lane's 16 units,
        // then 2 shfl_xor across lg groups; v = hi-row + lo-row (lg==0).
        float lsum = 0.f;
        #pragma unroll
        for (int nt = 0; nt < 4; ++nt)
            #pragma unroll
            for (int j = 0; j < 4; ++j)
                lsum = fmaf(fmaxf(acc[nt][j], 0.f), wp_t[nt][j], lsum);
        lsum += __shfl_xor(lsum, 16);
        lsum += __shfl_xor(lsum, 32);
        float vv = accv[0] + accv[1];    // rows 0(hi),1(lo) live at lg==0
        if (lg == 0)
            lv[wid][t * 16 + li] = make_float2(lsum, vv);
    }

    asm volatile("s_waitcnt lgkmcnt(0)" ::: "memory");

    // ---- per-wave softmax fused with output ----
    float2 myv[5];
    float m = -INFINITY;
    #pragma unroll
    for (int k = 0; k < 5; ++k) {
        int p = lane + k * 64;
        if (p < NP) { myv[k] = lv[wid][p]; m = fmaxf(m, myv[k].x); }
        else        { myv[k] = make_float2(-INFINITY, 0.f); }
    }
    m = wave_max(m);

    float se = 0.f, sev = 0.f;
    #pragma unroll
    for (int k = 0; k < 5; ++k) {
        int p = lane + k * 64;
        if (p < NP) {
            float e = __expf(myv[k].x - m);
            se += e;
            sev = fmaf(e, myv[k].y, sev);
        }
    }
    se  = wave_sum(se);
    sev = wave_sum(sev);
    if (lane == 0)
        out[b] = sev / se + bfc[0];
}

extern "C" void kernel_launch(void* const* d_in, const int* in_sizes, int n_in,
                              void* d_out, int out_size, void* d_ws, size_t ws_size,
                              hipStream_t stream) {
    const float* x   = (const float*)d_in[0];
    const float* Wa  = (const float*)d_in[1];
    const float* ba  = (const float*)d_in[2];
    const float* Wp  = (const float*)d_in[3];
    // d_in[4] = bp  (unused: softmax shift-invariant)
    const float* Wfc = (const float*)d_in[5];
    const float* bfc = (const float*)d_in[6];
    float* out = (float*)d_out;
    short* ws  = (short*)d_ws;

    const int B = in_sizes[0] / (NF * ND);
    hipLaunchKernelGGL(afm_prep_kernel, dim3(1), dim3(64), 0, stream, Wa, Wfc, ws);
    hipLaunchKernelGGL(afm_mfma_kernel, dim3(B / BPB), dim3(NT), 0, stream,
                       x, ba, Wp, bfc, ws, out);
}

// Round 14
// 28.497 us; speedup vs baseline: 1.3626x; 1.2173x over previous
//
#include <hip/hip_runtime.h>
#include <hip/hip_bf16.h>
#include <math.h>

// AFM: B=4096, F=24, D=64, A=64, P=F*(F-1)/2=276
#define NF 24
#define ND 64
#define NA 64
#define NP 276
#define NPAD 288
#define NTILE 18
#define NT 256      // 4 waves per block; wave w handles batch blockIdx*4+w
#define BPB 4
#define XPITCH 72   // fp16 row pitch (144B: odd 16B-granule count -> spread)

typedef _Float16 f16x8 __attribute__((ext_vector_type(8)));
typedef _Float16 f16x4 __attribute__((ext_vector_type(4)));
typedef float    f32x4 __attribute__((ext_vector_type(4)));

// ---- DPP helpers for the final wave-wide softmax reduce ----
template <int CTRL, int RMASK>
__device__ __forceinline__ float dpp_add_step(float v) {
    int moved = __builtin_amdgcn_update_dpp(0, __float_as_int(v), CTRL, RMASK, 0xf, true);
    return v + __int_as_float(moved);
}
template <int CTRL, int RMASK>
__device__ __forceinline__ float dpp_max_step(float v) {
    int moved = __builtin_amdgcn_update_dpp(__float_as_int(v), __float_as_int(v), CTRL, RMASK, 0xf, false);
    return fmaxf(v, __int_as_float(moved));
}
__device__ __forceinline__ float wave_sum(float v) {
    v = dpp_add_step<0x111, 0xf>(v);   // row_shr 1
    v = dpp_add_step<0x112, 0xf>(v);   // row_shr 2
    v = dpp_add_step<0x114, 0xf>(v);   // row_shr 4
    v = dpp_add_step<0x118, 0xf>(v);   // row_shr 8
    v = dpp_add_step<0x142, 0xa>(v);   // row_bcast:15 -> rows 1,3
    v = dpp_add_step<0x143, 0xc>(v);   // row_bcast:31 -> rows 2,3
    return __int_as_float(__builtin_amdgcn_readlane(__float_as_int(v), 63));
}
__device__ __forceinline__ float wave_max(float v) {
    v = dpp_max_step<0x111, 0xf>(v);
    v = dpp_max_step<0x112, 0xf>(v);
    v = dpp_max_step<0x114, 0xf>(v);
    v = dpp_max_step<0x118, 0xf>(v);
    v = dpp_max_step<0x142, 0xa>(v);
    v = dpp_max_step<0x143, 0xc>(v);
    return __int_as_float(__builtin_amdgcn_readlane(__float_as_int(v), 63));
}

// ws layout (16-bit units):
//   [0, 4096)    waF:  [lane 64][chunk 8 = nt*2+kh][8 f16]
//   [4096, 5120) wfcF: [lane 64][kh 2][8 f16]  (row0=hi, row1=lo as A-operand)
//   [5120, 5696) rc:   288 ints, packed (r<<16)|c, pad pairs = (0,0)
__global__ __launch_bounds__(64) void afm_prep_kernel(
    const float* __restrict__ Wa,
    const float* __restrict__ Wfc,
    unsigned short* __restrict__ ws)
{
    const int l  = (int)threadIdx.x;
    const int lg = l >> 4, li = l & 15;
    _Float16* waF  = (_Float16*)ws;
    _Float16* wfcF = (_Float16*)(ws + 64 * 64);
    int*      rc   = (int*)(ws + 64 * 64 + 64 * 16);
    #pragma unroll
    for (int nt = 0; nt < 4; ++nt)
        #pragma unroll
        for (int kh = 0; kh < 2; ++kh)
            #pragma unroll
            for (int i = 0; i < 8; ++i) {
                int d = kh * 32 + lg * 8 + i;
                waF[l * 64 + (nt * 2 + kh) * 8 + i] = (_Float16)Wa[d * NA + nt * 16 + li];
            }
    #pragma unroll
    for (int kh = 0; kh < 2; ++kh)
        #pragma unroll
        for (int i = 0; i < 8; ++i) {
            int d = kh * 32 + lg * 8 + i;
            float w = Wfc[d];
            _Float16 hi = (_Float16)w;
            _Float16 lo = (_Float16)(w - (float)hi);
            wfcF[l * 16 + kh * 8 + i] = (li == 0) ? hi : ((li == 1) ? lo : (_Float16)0.f);
        }
    for (int p0 = l; p0 < NPAD; p0 += 64) {
        int r = 0, c = 0;
        if (p0 < NP) {
            int rem = p0;
            while (rem >= NF - 1 - r) { rem -= NF - 1 - r; ++r; }
            c = r + 1 + rem;
        }
        rc[p0] = (r << 16) | c;
    }
}

__global__ __launch_bounds__(NT) void afm_mfma_kernel(
    const float* __restrict__ x,
    const float* __restrict__ ba,
    const float* __restrict__ Wp,
    const float* __restrict__ bfc,
    const unsigned short* __restrict__ ws,
    float* __restrict__ out)
{
    const int tid  = (int)threadIdx.x;
    const int lane = tid & 63;
    const int wid  = tid >> 6;
    const int b    = blockIdx.x * BPB + wid;   // this wave's batch
    const int lg   = lane >> 4;
    const int li   = lane & 15;

    __shared__ _Float16 xs[BPB][NF][XPITCH];  // per-wave fp16 x tile
    __shared__ float2   lv[BPB][NPAD];        // per-wave {logit, v}

    // ---- stage x[b] into LDS as fp16 (cvt once here) ----
    const float4* xb4 = (const float4*)(x + (size_t)b * (NF * ND));
    #pragma unroll
    for (int k = 0; k < 6; ++k) {
        int i = lane + k * 64;           // 0..383 float4s
        float4 v = xb4[i];
        f16x4 hv = { (_Float16)v.x, (_Float16)v.y, (_Float16)v.z, (_Float16)v.w };
        *(f16x4*)&xs[wid][i >> 4][(i & 15) * 4] = hv;   // 8B-aligned
    }

    // ---- fragments from ws: 10 vector loads, no cvt ----
    const f16x8* waF  = (const f16x8*)ws;              // [64][8]
    const f16x8* wfcF = (const f16x8*)(ws + 64 * 64);  // [64][2]
    const int*   rcg  = (const int*)(ws + 64 * 64 + 64 * 16);
    f16x8 WaF[4][2];
    #pragma unroll
    for (int nt = 0; nt < 4; ++nt)
        #pragma unroll
        for (int kh = 0; kh < 2; ++kh)
            WaF[nt][kh] = waF[lane * 8 + nt * 2 + kh];
    f16x8 WfcF[2] = { wfcF[lane * 2 + 0], wfcF[lane * 2 + 1] };

    // per-lane unit arrays: unit = nt*16 + lg*4 + j  (C/D row under swapped MFMA)
    float ba_t[4][4], wp_t[4][4];
    #pragma unroll
    for (int nt = 0; nt < 4; ++nt)
        #pragma unroll
        for (int j = 0; j < 4; ++j) {
            ba_t[nt][j] = ba[nt * 16 + lg * 4 + j];
            wp_t[nt][j] = Wp[nt * 16 + lg * 4 + j];
        }

    // hoisted pair table (18 ints)
    int prt[NTILE];
    #pragma unroll
    for (int t = 0; t < NTILE; ++t) prt[t] = rcg[t * 16 + li];

    // in-wave ordering of staging writes vs tile reads
    asm volatile("s_waitcnt lgkmcnt(0)" ::: "memory");

    // ---- tile loop: ip(fp16, pk_mul) -> D = Wa^T@ip^T (+ba) -> logits, v ----
    for (int t = 0; t < NTILE; ++t) {
        int pr = prt[t];
        int rI = pr >> 16, cI = pr & 0xffff;

        f16x8 Ah[2];
        #pragma unroll
        for (int kh = 0; kh < 2; ++kh) {
            int d0 = kh * 32 + lg * 8;
            f16x8 rv = *(const f16x8*)&xs[wid][rI][d0];   // 1 ds_read_b128
            f16x8 cv = *(const f16x8*)&xs[wid][cI][d0];   // 1 ds_read_b128
            Ah[kh] = rv * cv;                             // 4 v_pk_mul_f16
        }

        // swapped operands: A = Wa^T fragment, B = ip fragment. D[unit, pair].
        f32x4 acc[4];
        #pragma unroll
        for (int nt = 0; nt < 4; ++nt) {
            acc[nt] = (f32x4){ba_t[nt][0], ba_t[nt][1], ba_t[nt][2], ba_t[nt][3]};
            acc[nt] = __builtin_amdgcn_mfma_f32_16x16x32_f16(WaF[nt][0], Ah[0], acc[nt], 0, 0, 0);
            acc[nt] = __builtin_amdgcn_mfma_f32_16x16x32_f16(WaF[nt][1], Ah[1], acc[nt], 0, 0, 0);
        }
        f32x4 accv = (f32x4){0.f, 0.f, 0.f, 0.f};
        accv = __builtin_amdgcn_mfma_f32_16x16x32_f16(WfcF[0], Ah[0], accv, 0, 0, 0);
        accv = __builtin_amdgcn_mfma_f32_16x16x32_f16(WfcF[1], Ah[1], accv, 0, 0, 0);

        // epilogue: within-lane relu+Wp dot over this lane's 16 units,
        // then 2 shfl_xor across lg groups; v = hi-row + lo-row (lg==0).
        float lsum = 0.f;
        #pragma unroll
        for (int nt = 0; nt < 4; ++nt)
            #pragma unroll
            for (int j = 0; j < 4; ++j)
                lsum = fmaf(fmaxf(acc[nt][j], 0.f), wp_t[nt][j], lsum);
        lsum += __shfl_xor(lsum, 16);
        lsum += __shfl_xor(lsum, 32);
        float vv = accv[0] + accv[1];    // rows 0(hi),1(lo) live at lg==0
        if (lg == 0)
            lv[wid][t * 16 + li] = make_float2(lsum, vv);
    }

    asm volatile("s_waitcnt lgkmcnt(0)" ::: "memory");

    // ---- per-wave softmax fused with output ----
    float2 myv[5];
    float m = -INFINITY;
    #pragma unroll
    for (int k = 0; k < 5; ++k) {
        int p = lane + k * 64;
        if (p < NP) { myv[k] = lv[wid][p]; m = fmaxf(m, myv[k].x); }
        else        { myv[k] = make_float2(-INFINITY, 0.f); }
    }
    m = wave_max(m);

    float se = 0.f, sev = 0.f;
    #pragma unroll
    for (int k = 0; k < 5; ++k) {
        int p = lane + k * 64;
        if (p < NP) {
            float e = __expf(myv[k].x - m);
            se += e;
            sev = fmaf(e, myv[k].y, sev);
        }
    }
    se  = wave_sum(se);
    sev = wave_sum(sev);
    if (lane == 0)
        out[b] = sev / se + bfc[0];
}

extern "C" void kernel_launch(void* const* d_in, const int* in_sizes, int n_in,
                              void* d_out, int out_size, void* d_ws, size_t ws_size,
                              hipStream_t stream) {
    const float* x   = (const float*)d_in[0];
    const float* Wa  = (const float*)d_in[1];
    const float* ba  = (const float*)d_in[2];
    const float* Wp  = (const float*)d_in[3];
    // d_in[4] = bp  (unused: softmax shift-invariant)
    const float* Wfc = (const float*)d_in[5];
    const float* bfc = (const float*)d_in[6];
    float* out = (float*)d_out;
    unsigned short* ws = (unsigned short*)d_ws;

    const int B = in_sizes[0] / (NF * ND);
    hipLaunchKernelGGL(afm_prep_kernel, dim3(1), dim3(64), 0, stream, Wa, Wfc, ws);
    hipLaunchKernelGGL(afm_mfma_kernel, dim3(B / BPB), dim3(NT), 0, stream,
                       x, ba, Wp, bfc, ws, out);
}